// Round 9
// baseline (205.743 us; speedup 1.0000x reference)
//
#include <hip/hip_runtime.h>

// Shapes (fixed):
//   prev/next: [8, 32, 48, 48, 48] f32
//   phi:       [8, 1, 96, 96, 96] f32
//   stream:    [8, 3, 96, 96, 96] f32
// Outputs concatenated in d_out (f32): corr [8,27,48^3], vel/vel_phi/vel_stream [8,3,94^3]
//
// Model (confirmed R8): wall = wave-vmem-instruction issue (~24 cy/instr),
// valid while VGPR bin keeps 8 waves/SIMD and blocks keep CUs fed.
// R9: corr = R8 (f4, 10 loads/4 sites). vel = t-block4 with minimal windows
// (25 loads + 9 stores per 4 outputs; rows needing elems 1..4 use ONE
// dword-aligned f4). Tail t=92..93 separate segment. nt stores kept.

typedef float f2 __attribute__((ext_vector_type(2)));
typedef float f4 __attribute__((ext_vector_type(4)));
typedef float f4a __attribute__((ext_vector_type(4), aligned(4)));   // dword-aligned loads
typedef float f4u __attribute__((ext_vector_type(4), aligned(8)));   // 8B-aligned stores

constexpr int CB = 8, CC = 32, CX = 48, CY = 48, CZ = 48;
constexpr int H = 96, O = 94;
constexpr int PLANE = CY * CZ;       // 2304
constexpr int CSTR  = CX * PLANE;    // 110592
constexpr int HP    = H * H;         // 9216
constexpr size_t O3 = (size_t)O * O * O;

constexpr int CORR_NWG   = (CB * CX * CY * (CZ / 4)) / 256;   // 864
constexpr int VELM_TOTAL = CB * O * O * 23;                   // 1,625,824 (t=0..91)
constexpr int VELM_NWG   = (VELM_TOTAL + 255) / 256;          // 6351
constexpr int VELT_TOTAL = CB * O * O;                        // 70,688 (t=92,93)
constexpr int VELT_NWG   = (VELT_TOTAL + 255) / 256;          // 277

// ---------------------------------------------------------------------------
// corr (R8, unchanged): thread owns (b,x,y,z4*4..+3); 10 f4 loads per c-step,
// clamped-safe tap addresses zeroed via epilogue scale.
// ---------------------------------------------------------------------------
__device__ __forceinline__ void corr_body(
    int bid, const float* __restrict__ prev, const float* __restrict__ nxt,
    float* __restrict__ corr)
{
    constexpr int Z4 = CZ / 4;                       // 12
    int swz = (bid & 7) * (CORR_NWG / 8) + (bid >> 3);
    int idx = swz * 256 + (int)threadIdx.x;
    int z4 = idx % Z4; int r = idx / Z4;
    int y = r % CY; r /= CY;
    int x = r % CX; int b = r / CX;

    const size_t bbase = (size_t)b * CC * CSTR;
    const float* __restrict__ nbase = nxt + bbase;
    const float* pp = prev + bbase + (size_t)x * PLANE + (size_t)y * CZ + z4 * 4;

    const float* tp[9];
    float scj[9];
#pragma unroll
    for (int a = 0; a < 3; ++a) {
        int xx = x + a - 1;
        bool vx = (unsigned)xx < (unsigned)CX;
#pragma unroll
        for (int d = 0; d < 3; ++d) {
            int yy = y + d - 1;
            bool ok = vx && ((unsigned)yy < (unsigned)CY);
            tp[a * 3 + d] = nbase + (size_t)(ok ? xx : x) * PLANE
                                  + (size_t)(ok ? yy : y) * CZ + z4 * 4;
            scj[a * 3 + d] = ok ? (1.0f / 32.0f) : 0.0f;
        }
    }

    f4 acc[9];
#pragma unroll
    for (int jj = 0; jj < 9; ++jj) acc[jj] = f4{0.f, 0.f, 0.f, 0.f};

#pragma unroll 2
    for (int c = 0; c < CC; ++c) {
        f4 pv = *reinterpret_cast<const f4*>(pp);
#pragma unroll
        for (int jj = 0; jj < 9; ++jj) {
            f4 nv = *reinterpret_cast<const f4*>(tp[jj]);
            acc[jj] += pv * nv;
            tp[jj] += CSTR;
        }
        pp += CSTR;
    }

    const size_t obase = (size_t)b * 27 * CSTR + (size_t)x * PLANE
                       + (size_t)y * CZ + z4 * 4;
#pragma unroll
    for (int jj = 0; jj < 9; ++jj) {
        f4 v = acc[jj] * scj[jj];
        f4 gm = v; if (z4 == Z4 - 1) gm.w = 0.f;     // k=-1: zero z==47
        f4 gp = v; if (z4 == 0)      gp.x = 0.f;     // k=+1: zero z==0
        __builtin_nontemporal_store(gm, (f4*)(corr + obase + (size_t)jj * CSTR));
        __builtin_nontemporal_store(v,  (f4*)(corr + obase + (size_t)(9 + jj) * CSTR));
        __builtin_nontemporal_store(gp, (f4*)(corr + obase + (size_t)(18 + jj) * CSTR));
    }
}

// el6: element e (0..5) of an f4+f2 pair; e must be unroll-constant.
#define EL6(A, B_, e) ((e) < 4 ? (A)[(e)] : (B_)[(e) - 4])
// el5w: element m (1..5) of a window f4a loaded at +1 plus scalar at +5.
#define EL5W(W, E, m) ((m) < 5 ? (W)[(m) - 1] : (E))

__device__ __forceinline__ void velm_body(
    int bid, const float* __restrict__ phi, const float* __restrict__ stm,
    float* __restrict__ vel, float* __restrict__ vphi, float* __restrict__ vstr)
{
    const int q = VELM_NWG >> 3, rr = VELM_NWG & 7;  // 793, 7
    int xcd = bid & 7, g = bid >> 3;
    int swz = (xcd < rr) ? (xcd * (q + 1) + g) : (rr * (q + 1) + (xcd - rr) * q + g);
    int idx = swz * 256 + (int)threadIdx.x;
    if (idx >= VELM_TOTAL) return;
    int tt = idx % 23; int r2 = idx / 23;
    int j = r2 % O; r2 /= O;
    int i = r2 % O; int b = r2 / O;
    const int t = 4 * tt;

    const size_t hc = (size_t)H * HP;
    const float* ph = phi + (size_t)b * hc;
    const float* s0 = stm + (size_t)b * 3 * hc;
    const float* s1 = s0 + hc;
    const float* s2 = s1 + hc;
    const size_t ctr = (size_t)(i + 1) * HP + (size_t)(j + 1) * H + t;

    const size_t oo = ((size_t)i * O + j) * O + t;
    const size_t b3 = (size_t)b * 3;

    // ---- phi phase ----
    f4 c11a = *(const f4*)(ph + ctr);
    f2 c11b = *(const f2*)(ph + ctr + 4);
    f4a r12w = *(const f4a*)(ph + ctr + H + 1);
    f4a r10w = *(const f4a*)(ph + ctr - H + 1);
    f4a r21w = *(const f4a*)(ph + ctr + HP + 1);
    f4a r01w = *(const f4a*)(ph + ctr - HP + 1);
    float mup[4], mvp[4], mwp[4];
#pragma unroll
    for (int o = 0; o < 4; ++o) {
        mup[o] = (EL6(c11a, c11b, o + 2) - EL6(c11a, c11b, o)) * 0.5f;
        mvp[o] = (r12w[o] - r10w[o]) * 0.5f;
        mwp[o] = (r21w[o] - r01w[o]) * 0.5f;
    }
    __builtin_nontemporal_store(f4u{mup[0], mup[1], mup[2], mup[3]}, (f4u*)(vphi + (b3 + 0) * O3 + oo));
    __builtin_nontemporal_store(f4u{mvp[0], mvp[1], mvp[2], mvp[3]}, (f4u*)(vphi + (b3 + 1) * O3 + oo));
    __builtin_nontemporal_store(f4u{mwp[0], mwp[1], mwp[2], mwp[3]}, (f4u*)(vphi + (b3 + 2) * O3 + oo));

    // ---- u = d_x s1 - d_y s0 (needs k=0..4; A1_11/A0_11 kept to elem 5) ----
    f4 A1_21 = *(const f4*)(s1 + ctr + HP);  float A1_21e = (s1 + ctr + HP)[4];
    f4 A1_11 = *(const f4*)(s1 + ctr);       f2 A1_11b = *(const f2*)(s1 + ctr + 4);
    f4 A0_12 = *(const f4*)(s0 + ctr + H);   float A0_12e = (s0 + ctr + H)[4];
    f4 A0_11 = *(const f4*)(s0 + ctr);       f2 A0_11b = *(const f2*)(s0 + ctr + 4);
    float u[5];
#pragma unroll
    for (int k = 0; k < 5; ++k)
        u[k] = ((k < 4 ? A1_21[k] : A1_21e) - EL6(A1_11, A1_11b, k))
             - ((k < 4 ? A0_12[k] : A0_12e) - EL6(A0_11, A0_11b, k));
    float mus[4];
#pragma unroll
    for (int o = 0; o < 4; ++o) mus[o] = (u[o + 1] + u[o]) * 0.5f;
    __builtin_nontemporal_store(f4u{mus[0], mus[1], mus[2], mus[3]}, (f4u*)(vstr + (b3 + 0) * O3 + oo));
    __builtin_nontemporal_store(f4u{mup[0] + mus[0], mup[1] + mus[1], mup[2] + mus[2], mup[3] + mus[3]},
                                (f4u*)(vel + (b3 + 0) * O3 + oo));

    // ---- v = d_t s0 - d_x s2 ----
    f4a B0_10w = *(const f4a*)(s0 + ctr - H + 1);  float B0_10e = (s0 + ctr - H)[5];
    f4a B2_21w = *(const f4a*)(s2 + ctr + HP + 1);
    f4a B2_11w = *(const f4a*)(s2 + ctr + 1);
    f4a B2_20w = *(const f4a*)(s2 + ctr + HP - H + 1);
    f4a B2_10w = *(const f4a*)(s2 + ctr - H + 1);
    float mvs[4];
#pragma unroll
    for (int o = 0; o < 4; ++o) {
        float v1 = (EL6(A0_11, A0_11b, o + 2) - EL6(A0_11, A0_11b, o + 1))
                 - (B2_21w[o] - B2_11w[o]);
        float v0 = (EL5W(B0_10w, B0_10e, o + 2) - EL5W(B0_10w, B0_10e, o + 1))
                 - (B2_20w[o] - B2_10w[o]);
        mvs[o] = (v1 + v0) * 0.5f;
    }
    __builtin_nontemporal_store(f4u{mvs[0], mvs[1], mvs[2], mvs[3]}, (f4u*)(vstr + (b3 + 1) * O3 + oo));
    __builtin_nontemporal_store(f4u{mvp[0] + mvs[0], mvp[1] + mvs[1], mvp[2] + mvs[2], mvp[3] + mvs[3]},
                                (f4u*)(vel + (b3 + 1) * O3 + oo));

    // ---- w = d_y s2 - d_t s1 ----
    f4a C2_12w = *(const f4a*)(s2 + ctr + H + 1);
    f4a C2_02w = *(const f4a*)(s2 + ctr - HP + H + 1);
    f4a C2_01w = *(const f4a*)(s2 + ctr - HP + 1);
    f4a C1_01w = *(const f4a*)(s1 + ctr - HP + 1);  float C1_01e = (s1 + ctr - HP)[5];
    float mws[4];
#pragma unroll
    for (int o = 0; o < 4; ++o) {
        float w1 = (C2_12w[o] - B2_11w[o])
                 - (EL6(A1_11, A1_11b, o + 2) - EL6(A1_11, A1_11b, o + 1));
        float w0 = (C2_02w[o] - C2_01w[o])
                 - (EL5W(C1_01w, C1_01e, o + 2) - EL5W(C1_01w, C1_01e, o + 1));
        mws[o] = (w1 + w0) * 0.5f;
    }
    __builtin_nontemporal_store(f4u{mws[0], mws[1], mws[2], mws[3]}, (f4u*)(vstr + (b3 + 2) * O3 + oo));
    __builtin_nontemporal_store(f4u{mwp[0] + mws[0], mwp[1] + mws[1], mwp[2] + mws[2], mwp[3] + mws[3]},
                                (f4u*)(vel + (b3 + 2) * O3 + oo));
}

// ---------------------------------------------------------------------------
// vel tail: t = 92,93. Windows 92..95 -> one aligned f4 per row (R4, proven).
// ---------------------------------------------------------------------------
__device__ __forceinline__ void velt_body(
    int bid, const float* __restrict__ phi, const float* __restrict__ stm,
    float* __restrict__ vel, float* __restrict__ vphi, float* __restrict__ vstr)
{
    int idx = bid * 256 + (int)threadIdx.x;
    if (idx >= VELT_TOTAL) return;
    int j = idx % O; int r2 = idx / O;
    int i = r2 % O; int b = r2 / O;
    const int t = 92;

    const size_t hc = (size_t)H * HP;
    const float* ph = phi + (size_t)b * hc;
    const float* s0 = stm + (size_t)b * 3 * hc;
    const float* s1 = s0 + hc;
    const float* s2 = s1 + hc;
    const size_t ctr = (size_t)(i + 1) * HP + (size_t)(j + 1) * H + t;

#define L4(p) (*reinterpret_cast<const f4*>(p))
    f4 c11 = L4(ph + ctr), r12 = L4(ph + ctr + H), r10 = L4(ph + ctr - H);
    f4 r21 = L4(ph + ctr + HP), r01 = L4(ph + ctr - HP);
    f4 b1_21 = L4(s1 + ctr + HP), b1_11 = L4(s1 + ctr), b1_01 = L4(s1 + ctr - HP);
    f4 b0_12 = L4(s0 + ctr + H), b0_11 = L4(s0 + ctr), b0_10 = L4(s0 + ctr - H);
    f4 b2_21 = L4(s2 + ctr + HP), b2_11 = L4(s2 + ctr), b2_20 = L4(s2 + ctr + HP - H);
    f4 b2_10 = L4(s2 + ctr - H), b2_12 = L4(s2 + ctr + H), b2_02 = L4(s2 + ctr - HP + H);
    f4 b2_01 = L4(s2 + ctr - HP);
#undef L4

    float mup[2], mvp[2], mwp[2], mus[2], mvs[2], mws[2];
    float u[3];
#pragma unroll
    for (int k = 0; k < 3; ++k)
        u[k] = (b1_21[k] - b1_11[k]) - (b0_12[k] - b0_11[k]);
#pragma unroll
    for (int o = 0; o < 2; ++o) {
        mup[o] = (c11[o + 2] - c11[o]) * 0.5f;
        mvp[o] = (r12[o + 1] - r10[o + 1]) * 0.5f;
        mwp[o] = (r21[o + 1] - r01[o + 1]) * 0.5f;
        mus[o] = (u[o + 1] + u[o]) * 0.5f;
        float v1 = (b0_11[o + 2] - b0_11[o + 1]) - (b2_21[o + 1] - b2_11[o + 1]);
        float v0 = (b0_10[o + 2] - b0_10[o + 1]) - (b2_20[o + 1] - b2_10[o + 1]);
        mvs[o] = (v1 + v0) * 0.5f;
        float w1 = (b2_12[o + 1] - b2_11[o + 1]) - (b1_11[o + 2] - b1_11[o + 1]);
        float w0 = (b2_02[o + 1] - b2_01[o + 1]) - (b1_01[o + 2] - b1_01[o + 1]);
        mws[o] = (w1 + w0) * 0.5f;
    }

    const size_t oo = ((size_t)i * O + j) * O + t;
    const size_t b3 = (size_t)b * 3;
    __builtin_nontemporal_store(f2{mup[0], mup[1]}, (f2*)(vphi + (b3 + 0) * O3 + oo));
    __builtin_nontemporal_store(f2{mvp[0], mvp[1]}, (f2*)(vphi + (b3 + 1) * O3 + oo));
    __builtin_nontemporal_store(f2{mwp[0], mwp[1]}, (f2*)(vphi + (b3 + 2) * O3 + oo));
    __builtin_nontemporal_store(f2{mus[0], mus[1]}, (f2*)(vstr + (b3 + 0) * O3 + oo));
    __builtin_nontemporal_store(f2{mvs[0], mvs[1]}, (f2*)(vstr + (b3 + 1) * O3 + oo));
    __builtin_nontemporal_store(f2{mws[0], mws[1]}, (f2*)(vstr + (b3 + 2) * O3 + oo));
    __builtin_nontemporal_store(f2{mup[0] + mus[0], mup[1] + mus[1]}, (f2*)(vel + (b3 + 0) * O3 + oo));
    __builtin_nontemporal_store(f2{mvp[0] + mvs[0], mvp[1] + mvs[1]}, (f2*)(vel + (b3 + 1) * O3 + oo));
    __builtin_nontemporal_store(f2{mwp[0] + mws[0], mwp[1] + mws[1]}, (f2*)(vel + (b3 + 2) * O3 + oo));
}

__global__ __launch_bounds__(256) void fused_kernel(
    const float* __restrict__ prev, const float* __restrict__ nxt,
    const float* __restrict__ phi, const float* __restrict__ stm,
    float* __restrict__ corr, float* __restrict__ vel,
    float* __restrict__ vphi, float* __restrict__ vstr)
{
    int bid = blockIdx.x;
    if (bid < CORR_NWG) {
        corr_body(bid, prev, nxt, corr);
    } else if (bid < CORR_NWG + VELM_NWG) {
        velm_body(bid - CORR_NWG, phi, stm, vel, vphi, vstr);
    } else {
        velt_body(bid - CORR_NWG - VELM_NWG, phi, stm, vel, vphi, vstr);
    }
}

extern "C" void kernel_launch(void* const* d_in, const int* in_sizes, int n_in,
                              void* d_out, int out_size, void* d_ws, size_t ws_size,
                              hipStream_t stream)
{
    const float* prev = (const float*)d_in[0];
    const float* nxt  = (const float*)d_in[1];
    const float* phi  = (const float*)d_in[2];
    const float* stm  = (const float*)d_in[3];

    float* out = (float*)d_out;
    const size_t corr_sz = (size_t)CB * 27 * CX * CY * CZ;   // 23,887,872
    const size_t vel_sz  = (size_t)CB * 3 * O * O * O;       // 19,934,016
    float* corr = out;
    float* vel  = out + corr_sz;
    float* vphi = vel + vel_sz;
    float* vstr = vphi + vel_sz;

    fused_kernel<<<CORR_NWG + VELM_NWG + VELT_NWG, 256, 0, stream>>>(
        prev, nxt, phi, stm, corr, vel, vphi, vstr);
}